// Round 11
// baseline (139.849 us; speedup 1.0000x reference)
//
#include <hip/hip_runtime.h>

#define B 8
#define N 2048
#define D 64
#define BN (B*N)
#define CAP 64

// ---- node 1: scan -> lists (+ proj).  512 blocks x 1024 threads = exactly
// 2048 thr/CU (full residency, long-lived blocks).
// blocks [0,256): block = (b = bid>>5, chunk ck = bid&31) owns 64 columns over
//   the FULL j range.  Thread t: col-quad cq = t&15, j-segment js = t>>4
//   (32 rows).  Column bitmasks in LDS (thread-disjoint words, no atomics),
//   then 64 threads extract neighbor lists + exact degree.
// blocks [256,512): h0 = x @ U0 + b0, 64 rows/block, 4 rows/wave.
__global__ __launch_bounds__(1024, 8) void kScanProj(
        const float* __restrict__ adj, const float* __restrict__ x,
        const float* __restrict__ U0, const float* __restrict__ b0,
        unsigned short* __restrict__ cols, int* __restrict__ cnt,
        float* __restrict__ h0) {
    __shared__ unsigned sh[64 * 65 + 64];      // 16.9 KB, aliased by both paths
    const int tid = threadIdx.x;
    const int bid = blockIdx.x;
    if (bid < 256) {
        unsigned (*lmask)[65] = (unsigned(*)[65])sh;   // [64 cols][64 words]+pad
        int b  = bid >> 5, ck = bid & 31;
        int cq = tid & 15;                     // col quad within 64-col chunk
        int js = tid >> 4;                     // j segment [0,64): rows js*32..+31
        const float* base = adj + (size_t)b * N * N + (size_t)(js * 32) * N
                            + ck * 64 + cq * 4;
        unsigned w0 = 0, w1 = 0, w2 = 0, w3 = 0;
#pragma unroll 8
        for (int i = 0; i < 32; ++i) {         // 8 float4 loads in flight
            float4 v = *(const float4*)(base + (size_t)i * N);
            w0 |= (v.x != 0.f ? 1u : 0u) << i;
            w1 |= (v.y != 0.f ? 1u : 0u) << i;
            w2 |= (v.z != 0.f ? 1u : 0u) << i;
            w3 |= (v.w != 0.f ? 1u : 0u) << i;
        }
        lmask[cq * 4 + 0][js] = w0;            // thread-disjoint words
        lmask[cq * 4 + 1][js] = w1;
        lmask[cq * 4 + 2][js] = w2;
        lmask[cq * 4 + 3][js] = w3;
        __syncthreads();
        if (tid < 64) {                        // extract lists, j ascending
            int gcol = b * N + ck * 64 + tid;
            unsigned short* cl = cols + (size_t)gcol * CAP;
            int p = 0;
            for (int w = 0; w < 64; ++w) {
                unsigned m = lmask[tid][w];
                int jbase = w * 32;
                while (m) {
                    int t = __builtin_ctz(m);
                    m &= m - 1;
                    if (p < CAP) cl[p] = (unsigned short)(jbase + t);
                    ++p;
                }
            }
            cnt[gcol] = p;                     // exact degree (adj is {0,1})
        }
    } else {
        float* Uld = (float*)sh;               // 4096 floats
        float* bld = (float*)(sh + 4096);      // 64 floats
#pragma unroll
        for (int q = 0; q < 4; ++q) Uld[tid + q * 1024] = U0[tid + q * 1024];
        if (tid < D) bld[tid] = b0[tid];
        __syncthreads();
        int wid = tid >> 6, lane = tid & 63;
        int gw = (bid - 256) * 16 + wid;       // wave id [0, 4096)
#pragma unroll
        for (int rr = 0; rr < 4; ++rr) {
            int r = gw * 4 + rr;               // row [0, 16384)
            float xv = x[(size_t)r * D + lane];
            float o0 = bld[lane], o1 = 0.f, o2 = 0.f, o3 = 0.f;
#pragma unroll
            for (int k = 0; k < D; k += 4) {
                o0 = fmaf(__shfl(xv, k),     Uld[(k)     * D + lane], o0);
                o1 = fmaf(__shfl(xv, k + 1), Uld[(k + 1) * D + lane], o1);
                o2 = fmaf(__shfl(xv, k + 2), Uld[(k + 2) * D + lane], o2);
                o3 = fmaf(__shfl(xv, k + 3), Uld[(k + 3) * D + lane], o3);
            }
            h0[(size_t)r * D + lane] = (o0 + o1) + (o2 + o3);
        }
    }
}

// ---- GCN layer: 2 rows/wave, 16 gathers in flight + next-batch index
// prefetch.  All gather indices masked to [0,2048) (stale tail entries are
// garbage; predication discards their values, mask keeps reads in-bounds).
// 2048 blocks x 256 thr; block owns rows bid*8..+7.
// If pg != nullptr also writes pg[bid][d] = sum of this block's 8 output rows.
__global__ __launch_bounds__(256) void kL(const float* __restrict__ hin,
        const unsigned short* __restrict__ cols, const int* __restrict__ cnt,
        const float* __restrict__ U, float* __restrict__ hout,
        float* __restrict__ pg) {
    __shared__ float Uld[D * D];
    __shared__ float part[4][D];
    const int tid = threadIdx.x;
    const int bid = blockIdx.x;
#pragma unroll
    for (int q = 0; q < 16; ++q) Uld[tid + q * 256] = U[tid + q * 256];
    __syncthreads();
    int wid = tid >> 6, lane = tid & 63;
    int r0 = bid * 8 + wid * 2, r1 = r0 + 1;
    const float* hb = hin + ((size_t)(r0 >> 11) << 11) * D;   // batch base
    int ca = cnt[r0], cb = cnt[r1];
    int kma = ca < CAP ? ca : CAP, kmb = cb < CAP ? cb : CAP;
    const unsigned short* la = cols + (size_t)r0 * CAP;
    const unsigned short* lb = cols + (size_t)r1 * CAP;
    float acca = 0.f, accb = 0.f;
    int km = kma > kmb ? kma : kmb;
    uint4 wa = *(const uint4*)(la);
    uint4 wb = *(const uint4*)(lb);
    for (int k = 0; k < km; k += 8) {
        // prefetch next batch's indices (overrun stays inside cols/cnt ws)
        uint4 na = *(const uint4*)(la + k + 8);
        uint4 nb = *(const uint4*)(lb + k + 8);
        float a0 = hb[(size_t)(wa.x & 0x7ff)         * D + lane];
        float a1 = hb[(size_t)((wa.x >> 16) & 0x7ff) * D + lane];
        float a2 = hb[(size_t)(wa.y & 0x7ff)         * D + lane];
        float a3 = hb[(size_t)((wa.y >> 16) & 0x7ff) * D + lane];
        float a4 = hb[(size_t)(wa.z & 0x7ff)         * D + lane];
        float a5 = hb[(size_t)((wa.z >> 16) & 0x7ff) * D + lane];
        float a6 = hb[(size_t)(wa.w & 0x7ff)         * D + lane];
        float a7 = hb[(size_t)((wa.w >> 16) & 0x7ff) * D + lane];
        float b0_ = hb[(size_t)(wb.x & 0x7ff)         * D + lane];
        float b1_ = hb[(size_t)((wb.x >> 16) & 0x7ff) * D + lane];
        float b2_ = hb[(size_t)(wb.y & 0x7ff)         * D + lane];
        float b3_ = hb[(size_t)((wb.y >> 16) & 0x7ff) * D + lane];
        float b4_ = hb[(size_t)(wb.z & 0x7ff)         * D + lane];
        float b5_ = hb[(size_t)((wb.z >> 16) & 0x7ff) * D + lane];
        float b6_ = hb[(size_t)(wb.w & 0x7ff)         * D + lane];
        float b7_ = hb[(size_t)((wb.w >> 16) & 0x7ff) * D + lane];
        acca += ((k + 0 < kma ? a0 : 0.f) + (k + 1 < kma ? a1 : 0.f))
              + ((k + 2 < kma ? a2 : 0.f) + (k + 3 < kma ? a3 : 0.f))
              + ((k + 4 < kma ? a4 : 0.f) + (k + 5 < kma ? a5 : 0.f))
              + ((k + 6 < kma ? a6 : 0.f) + (k + 7 < kma ? a7 : 0.f));
        accb += ((k + 0 < kmb ? b0_ : 0.f) + (k + 1 < kmb ? b1_ : 0.f))
              + ((k + 2 < kmb ? b2_ : 0.f) + (k + 3 < kmb ? b3_ : 0.f))
              + ((k + 4 < kmb ? b4_ : 0.f) + (k + 5 < kmb ? b5_ : 0.f))
              + ((k + 6 < kmb ? b6_ : 0.f) + (k + 7 < kmb ? b7_ : 0.f));
        wa = na; wb = nb;
    }
    float oa0 = 0.f, oa1 = 0.f, oa2 = 0.f, oa3 = 0.f;
    float ob0 = 0.f, ob1 = 0.f, ob2 = 0.f, ob3 = 0.f;
#pragma unroll
    for (int d = 0; d < D; d += 4) {           // 8 independent fma chains
        oa0 = fmaf(__shfl(acca, d),     Uld[(d)     * D + lane], oa0);
        ob0 = fmaf(__shfl(accb, d),     Uld[(d)     * D + lane], ob0);
        oa1 = fmaf(__shfl(acca, d + 1), Uld[(d + 1) * D + lane], oa1);
        ob1 = fmaf(__shfl(accb, d + 1), Uld[(d + 1) * D + lane], ob1);
        oa2 = fmaf(__shfl(acca, d + 2), Uld[(d + 2) * D + lane], oa2);
        ob2 = fmaf(__shfl(accb, d + 2), Uld[(d + 2) * D + lane], ob2);
        oa3 = fmaf(__shfl(acca, d + 3), Uld[(d + 3) * D + lane], oa3);
        ob3 = fmaf(__shfl(accb, d + 3), Uld[(d + 3) * D + lane], ob3);
    }
    float outa = fmaxf(((oa0 + oa1) + (oa2 + oa3)) / (float)ca, 0.f);
    float outb = fmaxf(((ob0 + ob1) + (ob2 + ob3)) / (float)cb, 0.f);
    hout[(size_t)r0 * D + lane] = outa;
    hout[(size_t)r1 * D + lane] = outb;
    if (pg != nullptr) {
        part[wid][lane] = outa + outb;
        __syncthreads();
        if (wid == 0)
            pg[(size_t)bid * D + lane] =
                part[0][lane] + part[1][lane] + part[2][lane] + part[3][lane];
    }
}

// ---- head: 1 block x 512; wave w = batch w reduces its 256 pg partials ----
__global__ __launch_bounds__(512) void kHead(const float* __restrict__ pg,
        const float* __restrict__ Q, const float* __restrict__ P,
        float* __restrict__ out) {
    int wid = threadIdx.x >> 6, lane = threadIdx.x & 63;
    float md = 0.f;
#pragma unroll 8
    for (int k = 0; k < 256; ++k) md += pg[(size_t)(wid * 256 + k) * D + lane];
    md *= (1.0f / N);                           // m[b][lane]
    float t = 0.f;
#pragma unroll 8
    for (int k = 0; k < D; ++k) t = fmaf(Q[lane * D + k], __shfl(md, k), t);
    t = fmaxf(t, 0.f);
    float v = t * P[lane];
    for (int off = 32; off; off >>= 1) v += __shfl_down(v, off);
    if (lane == 0) out[wid] = v;
}

extern "C" void kernel_launch(void* const* d_in, const int* in_sizes, int n_in,
                              void* d_out, int out_size, void* d_ws, size_t ws_size,
                              hipStream_t stream) {
    const float* x   = (const float*)d_in[0];
    const float* adj = (const float*)d_in[1];
    const float* U0  = (const float*)d_in[2];
    const float* b0  = (const float*)d_in[3];
    const float* Us  = (const float*)d_in[4];
    const float* Q   = (const float*)d_in[5];
    const float* P   = (const float*)d_in[6];
    float* out = (float*)d_out;

    char* ws = (char*)d_ws;
    size_t off = 0;
    float* h0 = (float*)(ws + off); off += (size_t)BN * D * sizeof(float);  // 4 MB
    float* h1 = (float*)(ws + off); off += (size_t)BN * D * sizeof(float);  // 4 MB
    unsigned short* cols = (unsigned short*)(ws + off);
    off += (size_t)CAP * BN * sizeof(unsigned short);                       // 2 MB
    int* cnt = (int*)(ws + off); off += (size_t)BN * sizeof(int);           // 64 KB
    float* pg = (float*)(ws + off); off += (size_t)2048 * D * sizeof(float); // 512 KB

    kScanProj<<<512, 1024, 0, stream>>>(adj, x, U0, b0, cols, cnt, h0);
    kL<<<2048, 256, 0, stream>>>(h0, cols, cnt, Us + 0 * D * D, h1, nullptr);
    kL<<<2048, 256, 0, stream>>>(h1, cols, cnt, Us + 1 * D * D, h0, nullptr);
    kL<<<2048, 256, 0, stream>>>(h0, cols, cnt, Us + 2 * D * D, h1, pg);
    kHead<<<1, 512, 0, stream>>>(pg, Q, P, out);
}

// Round 12
// 117.941 us; speedup vs baseline: 1.1858x; 1.1858x over previous
//
#include <hip/hip_runtime.h>

#define B 8
#define N 2048
#define D 64
#define BN (B*N)
#define CAP 64

// ---- node 1: scan -> lists (+ proj).  768 blocks x 256 thr, no VGPR clamp.
// blocks [0,512): block = (b = bid>>6, ck = bid&63) owns 32 columns over the
//   full j range.  Thread: col-quad cq = tid&7 (4 cols), j-segment js = tid>>3
//   (64 rows).  Loads issued 16-deep into a register array (no spill), masks
//   accumulate in LDS (thread-disjoint words), 32 threads extract lists.
// blocks [512,768): h0 = x @ U0 + b0, 16 rows/wave.
__global__ __launch_bounds__(256) void kScanProj(
        const float* __restrict__ adj, const float* __restrict__ x,
        const float* __restrict__ U0, const float* __restrict__ b0,
        unsigned short* __restrict__ cols, int* __restrict__ cnt,
        float* __restrict__ h0) {
    __shared__ unsigned sh[4160];              // 16.6 KB, aliased by both paths
    const int tid = threadIdx.x;
    const int bid = blockIdx.x;
    if (bid < 512) {
        unsigned (*lmask)[65] = (unsigned(*)[65])sh;   // [32 cols][64 words +pad]
        int b  = bid >> 6, ck = bid & 63;
        int cq = tid & 7;                      // col quad within 32-col chunk
        int js = tid >> 3;                     // j segment [0,32): rows js*64..+63
        const float* base = adj + (size_t)b * N * N + (size_t)(js * 64) * N
                            + ck * 32 + cq * 4;
#pragma unroll
        for (int w = 0; w < 2; ++w) {          // 2 words of 32 rows each
            unsigned m0 = 0, m1 = 0, m2 = 0, m3 = 0;
            float4 v[16];
#pragma unroll
            for (int i = 0; i < 16; ++i)       // 16 loads in flight
                v[i] = *(const float4*)(base + (size_t)(w * 32 + i) * N);
#pragma unroll
            for (int i = 0; i < 16; ++i) {
                m0 |= (v[i].x != 0.f ? 1u : 0u) << i;
                m1 |= (v[i].y != 0.f ? 1u : 0u) << i;
                m2 |= (v[i].z != 0.f ? 1u : 0u) << i;
                m3 |= (v[i].w != 0.f ? 1u : 0u) << i;
            }
#pragma unroll
            for (int i = 0; i < 16; ++i)       // 16 more in flight
                v[i] = *(const float4*)(base + (size_t)(w * 32 + 16 + i) * N);
#pragma unroll
            for (int i = 0; i < 16; ++i) {
                m0 |= (v[i].x != 0.f ? 1u : 0u) << (16 + i);
                m1 |= (v[i].y != 0.f ? 1u : 0u) << (16 + i);
                m2 |= (v[i].z != 0.f ? 1u : 0u) << (16 + i);
                m3 |= (v[i].w != 0.f ? 1u : 0u) << (16 + i);
            }
            lmask[cq * 4 + 0][js * 2 + w] = m0;    // thread-disjoint words
            lmask[cq * 4 + 1][js * 2 + w] = m1;
            lmask[cq * 4 + 2][js * 2 + w] = m2;
            lmask[cq * 4 + 3][js * 2 + w] = m3;
        }
        __syncthreads();
        if (tid < 32) {                        // extract lists, j ascending
            int gcol = b * N + ck * 32 + tid;
            unsigned short* cl = cols + (size_t)gcol * CAP;
            int p = 0;
            for (int w = 0; w < 64; ++w) {
                unsigned m = lmask[tid][w];
                int jbase = w * 32;
                while (m) {
                    int t = __builtin_ctz(m);
                    m &= m - 1;
                    if (p < CAP) cl[p] = (unsigned short)(jbase + t);
                    ++p;
                }
            }
            cnt[gcol] = p;                     // exact degree (adj is {0,1})
        }
    } else {
        float* Uld = (float*)sh;               // 4096 floats
        float* bld = (float*)(sh + 4096);      // 64 floats
#pragma unroll
        for (int q = 0; q < 16; ++q) Uld[tid + q * 256] = U0[tid + q * 256];
        if (tid < D) bld[tid] = b0[tid];
        __syncthreads();
        int wid = tid >> 6, lane = tid & 63;
        int gw = (bid - 512) * 4 + wid;        // wave id [0, 1024)
        for (int rr = 0; rr < 16; ++rr) {
            int r = gw * 16 + rr;              // row [0, 16384)
            float xv = x[(size_t)r * D + lane];
            float o0 = bld[lane], o1 = 0.f, o2 = 0.f, o3 = 0.f;
#pragma unroll
            for (int k = 0; k < D; k += 4) {
                o0 = fmaf(__shfl(xv, k),     Uld[(k)     * D + lane], o0);
                o1 = fmaf(__shfl(xv, k + 1), Uld[(k + 1) * D + lane], o1);
                o2 = fmaf(__shfl(xv, k + 2), Uld[(k + 2) * D + lane], o2);
                o3 = fmaf(__shfl(xv, k + 3), Uld[(k + 3) * D + lane], o3);
            }
            h0[(size_t)r * D + lane] = (o0 + o1) + (o2 + o3);
        }
    }
}

// ---- GCN layer: 4 rows/wave -> 32 gathers + 4 index prefetches in flight.
// 1024 blocks x 256 thr; block owns rows bid*16..+15.  Indices masked to
// [0,2048) (stale tail entries discarded by predication).
// If pg != nullptr also writes pg[bid][d] = sum of this block's 16 output rows.
__global__ __launch_bounds__(256) void kL(const float* __restrict__ hin,
        const unsigned short* __restrict__ cols, const int* __restrict__ cnt,
        const float* __restrict__ U, float* __restrict__ hout,
        float* __restrict__ pg) {
    __shared__ float Uld[D * D];
    __shared__ float part[4][D];
    const int tid = threadIdx.x;
    const int bid = blockIdx.x;
#pragma unroll
    for (int q = 0; q < 16; ++q) Uld[tid + q * 256] = U[tid + q * 256];
    __syncthreads();
    int wid = tid >> 6, lane = tid & 63;
    int rbase = bid * 16 + wid * 4;
    const float* hb = hin + ((size_t)(rbase >> 11) << 11) * D;   // batch base
    int c[4], kmx[4];
    const unsigned short* cl[4];
#pragma unroll
    for (int q = 0; q < 4; ++q) {
        int r = rbase + q;
        c[q] = cnt[r];
        kmx[q] = c[q] < CAP ? c[q] : CAP;
        cl[q] = cols + (size_t)r * CAP;
    }
    int km01 = kmx[0] > kmx[1] ? kmx[0] : kmx[1];
    int km23 = kmx[2] > kmx[3] ? kmx[2] : kmx[3];
    int km = km01 > km23 ? km01 : km23;
    float acc[4] = {0.f, 0.f, 0.f, 0.f};
    uint4 w4[4];
#pragma unroll
    for (int q = 0; q < 4; ++q) w4[q] = *(const uint4*)(cl[q]);
    for (int k = 0; k < km; k += 8) {
        uint4 nx[4];
#pragma unroll
        for (int q = 0; q < 4; ++q) nx[q] = *(const uint4*)(cl[q] + k + 8);
#pragma unroll
        for (int q = 0; q < 4; ++q) {
            float a0 = hb[(size_t)(w4[q].x & 0x7ff)         * D + lane];
            float a1 = hb[(size_t)((w4[q].x >> 16) & 0x7ff) * D + lane];
            float a2 = hb[(size_t)(w4[q].y & 0x7ff)         * D + lane];
            float a3 = hb[(size_t)((w4[q].y >> 16) & 0x7ff) * D + lane];
            float a4 = hb[(size_t)(w4[q].z & 0x7ff)         * D + lane];
            float a5 = hb[(size_t)((w4[q].z >> 16) & 0x7ff) * D + lane];
            float a6 = hb[(size_t)(w4[q].w & 0x7ff)         * D + lane];
            float a7 = hb[(size_t)((w4[q].w >> 16) & 0x7ff) * D + lane];
            acc[q] += ((k + 0 < kmx[q] ? a0 : 0.f) + (k + 1 < kmx[q] ? a1 : 0.f))
                    + ((k + 2 < kmx[q] ? a2 : 0.f) + (k + 3 < kmx[q] ? a3 : 0.f))
                    + ((k + 4 < kmx[q] ? a4 : 0.f) + (k + 5 < kmx[q] ? a5 : 0.f))
                    + ((k + 6 < kmx[q] ? a6 : 0.f) + (k + 7 < kmx[q] ? a7 : 0.f));
        }
#pragma unroll
        for (int q = 0; q < 4; ++q) w4[q] = nx[q];
    }
    float rsum = 0.f;
#pragma unroll
    for (int q = 0; q < 4; ++q) {
        float o0 = 0.f, o1 = 0.f, o2 = 0.f, o3 = 0.f;
#pragma unroll
        for (int d = 0; d < D; d += 4) {       // 4 independent fma chains
            o0 = fmaf(__shfl(acc[q], d),     Uld[(d)     * D + lane], o0);
            o1 = fmaf(__shfl(acc[q], d + 1), Uld[(d + 1) * D + lane], o1);
            o2 = fmaf(__shfl(acc[q], d + 2), Uld[(d + 2) * D + lane], o2);
            o3 = fmaf(__shfl(acc[q], d + 3), Uld[(d + 3) * D + lane], o3);
        }
        float ov = fmaxf(((o0 + o1) + (o2 + o3)) / (float)c[q], 0.f);
        hout[(size_t)(rbase + q) * D + lane] = ov;
        rsum += ov;
    }
    if (pg != nullptr) {
        part[wid][lane] = rsum;
        __syncthreads();
        if (wid == 0)
            pg[(size_t)bid * D + lane] =
                part[0][lane] + part[1][lane] + part[2][lane] + part[3][lane];
    }
}

// ---- head: 1 block x 512; wave w = batch w reduces its 128 pg partials ----
__global__ __launch_bounds__(512) void kHead(const float* __restrict__ pg,
        const float* __restrict__ Q, const float* __restrict__ P,
        float* __restrict__ out) {
    int wid = threadIdx.x >> 6, lane = threadIdx.x & 63;
    float md = 0.f;
#pragma unroll 8
    for (int k = 0; k < 128; ++k) md += pg[(size_t)(wid * 128 + k) * D + lane];
    md *= (1.0f / N);                           // m[b][lane]
    float t = 0.f;
#pragma unroll 8
    for (int k = 0; k < D; ++k) t = fmaf(Q[lane * D + k], __shfl(md, k), t);
    t = fmaxf(t, 0.f);
    float v = t * P[lane];
    for (int off = 32; off; off >>= 1) v += __shfl_down(v, off);
    if (lane == 0) out[wid] = v;
}

extern "C" void kernel_launch(void* const* d_in, const int* in_sizes, int n_in,
                              void* d_out, int out_size, void* d_ws, size_t ws_size,
                              hipStream_t stream) {
    const float* x   = (const float*)d_in[0];
    const float* adj = (const float*)d_in[1];
    const float* U0  = (const float*)d_in[2];
    const float* b0  = (const float*)d_in[3];
    const float* Us  = (const float*)d_in[4];
    const float* Q   = (const float*)d_in[5];
    const float* P   = (const float*)d_in[6];
    float* out = (float*)d_out;

    char* ws = (char*)d_ws;
    size_t off = 0;
    float* h0 = (float*)(ws + off); off += (size_t)BN * D * sizeof(float);  // 4 MB
    float* h1 = (float*)(ws + off); off += (size_t)BN * D * sizeof(float);  // 4 MB
    unsigned short* cols = (unsigned short*)(ws + off);
    off += (size_t)CAP * BN * sizeof(unsigned short);                       // 2 MB
    int* cnt = (int*)(ws + off); off += (size_t)BN * sizeof(int);           // 64 KB
    float* pg = (float*)(ws + off); off += (size_t)1024 * D * sizeof(float); // 256 KB

    kScanProj<<<768, 256, 0, stream>>>(adj, x, U0, b0, cols, cnt, h0);
    kL<<<1024, 256, 0, stream>>>(h0, cols, cnt, Us + 0 * D * D, h1, nullptr);
    kL<<<1024, 256, 0, stream>>>(h1, cols, cnt, Us + 1 * D * D, h0, nullptr);
    kL<<<1024, 256, 0, stream>>>(h0, cols, cnt, Us + 2 * D * D, h1, pg);
    kHead<<<1, 512, 0, stream>>>(pg, Q, P, out);
}